// Round 5
// baseline (157.670 us; speedup 1.0000x reference)
//
#include <hip/hip_runtime.h>

typedef short short8 __attribute__((ext_vector_type(8)));
typedef unsigned short ushort8 __attribute__((ext_vector_type(8)));
typedef float f32x4 __attribute__((ext_vector_type(4)));

__device__ __forceinline__ unsigned short f32_to_bf16(float f) {
  unsigned u = __float_as_uint(f);
  unsigned r = 0x7fffu + ((u >> 16) & 1u);
  return (unsigned short)((u + r) >> 16);
}
__device__ __forceinline__ float bf16_to_f32(unsigned short h) {
  return __uint_as_float(((unsigned)h) << 16);
}

// ---------------- f32 -> bf16 convert (vectorized, 8 elems/thread) ----------
__global__ void cvt_f32_bf16(const float* __restrict__ s,
                             unsigned short* __restrict__ d, int n8) {
  int i = blockIdx.x * blockDim.x + threadIdx.x;
  if (i >= n8) return;
  const float4* sp = (const float4*)s;
  float4 a = sp[2 * i], b = sp[2 * i + 1];
  ushort8 o;
  o[0] = f32_to_bf16(a.x); o[1] = f32_to_bf16(a.y);
  o[2] = f32_to_bf16(a.z); o[3] = f32_to_bf16(a.w);
  o[4] = f32_to_bf16(b.x); o[5] = f32_to_bf16(b.y);
  o[6] = f32_to_bf16(b.z); o[7] = f32_to_bf16(b.w);
  ((ushort8*)d)[i] = o;
}

// ---------------- async global->LDS (16B/lane, wave-uniform LDS base) -------
__device__ __forceinline__ void gload_lds16(const void* g, void* l) {
  auto* gp = (const __attribute__((address_space(1))) uint32_t*)((uintptr_t)g);
  auto* lp = (__attribute__((address_space(3))) uint32_t*)(uint32_t)(uintptr_t)l;
  __builtin_amdgcn_global_load_lds(gp, lp, 16, 0, 0);
}

// ---------------- 16-point DFT (radix 4x4, constant twiddles) ---------------
constexpr float C16T[16] = {
    1.f,  0.9238795325112867f,  0.7071067811865476f,  0.3826834323650898f,
    0.f, -0.3826834323650898f, -0.7071067811865476f, -0.9238795325112867f,
   -1.f, -0.9238795325112867f, -0.7071067811865476f, -0.3826834323650898f,
    0.f,  0.3826834323650898f,  0.7071067811865476f,  0.9238795325112867f};
constexpr float S16T[16] = {
    0.f,  0.3826834323650898f,  0.7071067811865476f,  0.9238795325112867f,
    1.f,  0.9238795325112867f,  0.7071067811865476f,  0.3826834323650898f,
    0.f, -0.3826834323650898f, -0.7071067811865476f, -0.9238795325112867f,
   -1.f, -0.9238795325112867f, -0.7071067811865476f, -0.3826834323650898f};

__device__ __forceinline__ void dft16(const float* xr, const float* xi,
                                      float* Xr, float* Xi, const float sgn) {
  float Tr[4][4], Ti[4][4];
#pragma unroll
  for (int c0 = 0; c0 < 4; ++c0) {
    float ar = xr[c0],      ai = xi[c0];
    float br = xr[c0 + 4],  bi = xi[c0 + 4];
    float cr = xr[c0 + 8],  ci = xi[c0 + 8];
    float dr = xr[c0 + 12], di = xi[c0 + 12];
    float Er = ar + cr, Ei = ai + ci, Fr = ar - cr, Fi = ai - ci;
    float Gr = br + dr, Gi = bi + di, Hr = br - dr, Hi = bi - di;
    Tr[c0][0] = Er + Gr; Ti[c0][0] = Ei + Gi;
    Tr[c0][2] = Er - Gr; Ti[c0][2] = Ei - Gi;
    float wHr = -sgn * Hi, wHi = sgn * Hr;
    Tr[c0][1] = Fr + wHr; Ti[c0][1] = Fi + wHi;
    Tr[c0][3] = Fr - wHr; Ti[c0][3] = Fi - wHi;
  }
#pragma unroll
  for (int u = 0; u < 16; ++u) {
    const int m = u & 3;
    float sr = Tr[0][m], si = Ti[0][m];
#pragma unroll
    for (int c0 = 1; c0 < 4; ++c0) {
      const int k = (u * c0) & 15;
      const float wr = C16T[k];
      const float wi = sgn * S16T[k];
      sr += wr * Tr[c0][m] - wi * Ti[c0][m];
      si += wr * Ti[c0][m] + wi * Tr[c0][m];
    }
    Xr[u] = sr; Xi[u] = si;
  }
}

// ---------------- fold spectral filter into encoder weights -----------------
// Writes interleaved B'' [1536][768] bf16: for output-channel c,
//   re -> row (c>>5)*64 + (c&31),  im -> row (c>>5)*64 + 32 + (c&31).
__global__ __launch_bounds__(256) void fold_filter(
    const float* __restrict__ We, const float* __restrict__ be,
    const float* __restrict__ fre, const float* __restrict__ fim,
    unsigned short* __restrict__ Bpp, float* __restrict__ be_re,
    float* __restrict__ be_im) {
  __shared__ float2 S[16 * 276];
  const int tid = threadIdx.x;
  const int p = tid >> 4;
  const int q = tid & 15;
  const int item = blockIdx.x * 16 + p;
  const bool isW = item < 2304;
  const bool isB = (item >= 2304) && (item < 2307);
  const int e = isW ? (item / 3) : 0;
  const int ch = isW ? (item % 3) : (isB ? (item - 2304) : 0);
  const int sb = p * 276;

  {
    float xr[16], xi[16], Xr[16], Xi[16];
#pragma unroll
    for (int c = 0; c < 16; ++c) {
      const int crow = ch * 256 + q * 16 + c;
      xr[c] = isW ? We[(size_t)crow * 768 + e] : be[crow];
      xi[c] = 0.f;
    }
    dft16(xr, xi, Xr, Xi, -1.f);
#pragma unroll
    for (int u = 0; u < 16; ++u) S[sb + q * 17 + u] = make_float2(Xr[u], Xi[u]);
  }
  __syncthreads();

  {
    float xr[16], xi[16], Xr[16], Xi[16];
#pragma unroll
    for (int k = 0; k < 16; ++k) {
      float2 t = S[sb + k * 17 + q];
      xr[k] = t.x; xi[k] = t.y;
    }
    dft16(xr, xi, Xr, Xi, -1.f);
#pragma unroll
    for (int v = 0; v < 16; ++v) {
      float fr = fre[v * 16 + q], fi = fim[v * 16 + q];
      float tr = Xr[v] * fr - Xi[v] * fi;
      float ti = Xr[v] * fi + Xi[v] * fr;
      xr[v] = tr; xi[v] = ti;
    }
    dft16(xr, xi, Xr, Xi, 1.f);
#pragma unroll
    for (int r = 0; r < 16; ++r) S[sb + r * 17 + q] = make_float2(Xr[r], Xi[r]);
  }
  __syncthreads();

  {
    float xr[16], xi[16], Xr[16], Xi[16];
#pragma unroll
    for (int u = 0; u < 16; ++u) {
      float2 t = S[sb + q * 17 + u];
      xr[u] = t.x; xi[u] = t.y;
    }
    dft16(xr, xi, Xr, Xi, 1.f);
#pragma unroll
    for (int c = 0; c < 16; ++c) {
      const int crow = ch * 256 + q * 16 + c;
      const float rr = Xr[c] * (1.f / 256.f);
      const float ri = Xi[c] * (1.f / 256.f);
      if (isW) {
        const size_t rre = (size_t)(crow >> 5) * 64 + (crow & 31);
        Bpp[(rre)*768 + e]      = f32_to_bf16(rr);
        Bpp[(rre + 32)*768 + e] = f32_to_bf16(ri);
      } else if (isB) {
        be_re[crow] = rr;
        be_im[crow] = ri;
      }
    }
  }
}

// ---------------- depth-3 pipelined MFMA GEMM --------------------------------
// C = A[M,K] * B[NB,K]^T. Tile 256(M) x 128(B-rows), BK=64, 512 thr = 8 waves
// (4 wm x 2 wn), per-wave 64x64 output = 4x4 frags x 2 kk = 32 MFMA/K-tile.
// Triple-buffered LDS (144 KB), one raw s_barrier per K-tile, counted
// s_waitcnt vmcnt(6) (tile kt's loads issued 2 compute-periods earlier).
// Proven 8-slot XOR swizzle: LDS(row, slot s) holds global k-slot s^(row&7).
// ENC=1: B'' interleaved re/im, epilogue |.| -> bf16 out (ld 768).
// ENC=0: + bias, f32 out (ld 768).
template <int ENC>
__global__ __launch_bounds__(512, 2) void gemm_d3(
    const unsigned short* __restrict__ A, const unsigned short* __restrict__ B,
    const float* __restrict__ bias_re, const float* __restrict__ bias_im,
    void* __restrict__ out, int M, int K, int nbx) {
  __shared__ __align__(16) unsigned short As[3][256 * 64];
  __shared__ __align__(16) unsigned short Bs[3][128 * 64];

  const int tid = threadIdx.x;
  const int lane = tid & 63;
  const int wid = tid >> 6;          // 0..7
  const int wm = wid >> 1;           // 0..3 (64-row band)
  const int wn = wid & 1;            // 0..1 (64-col band)

  // bijective XCD swizzle (m204)
  const int nwg = gridDim.x;
  const int q8 = nwg >> 3, r8 = nwg & 7;
  const int xcd = blockIdx.x & 7, ii = blockIdx.x >> 3;
  const int lid = (xcd < r8 ? xcd * (q8 + 1) : r8 * (q8 + 1) + (xcd - r8) * q8) + ii;
  const int m0 = (lid / nbx) * 256;
  const int n0 = (lid % nbx) * 128;  // B-row tile base

  const int rr = (wid << 3) + (lane >> 3);      // staging row within 64-chunk
  const int sl = (lane & 7) ^ (lane >> 3);      // pre-swizzled 16B slot

  f32x4 acc[4][4] = {};

  auto STAGE = [&](int sb, int kt) {
    const int k0 = kt * 64 + sl * 8;
#pragma unroll
    for (int l = 0; l < 4; ++l)
      gload_lds16(A + (size_t)(m0 + l * 64 + rr) * K + k0,
                  &As[sb][(l * 64 + (wid << 3)) * 64]);
#pragma unroll
    for (int l = 0; l < 2; ++l)
      gload_lds16(B + (size_t)(n0 + l * 64 + rr) * K + k0,
                  &Bs[sb][(l * 64 + (wid << 3)) * 64]);
  };

  const int rsel = lane & 15;
  const int swz = (lane & 7) << 4;   // (row&7)<<4, since row&7 == lane&7
  auto COMPUTE = [&](int sb) {
    const char* Ab = (const char*)&As[sb][0];
    const char* Bb = (const char*)&Bs[sb][0];
#pragma unroll
    for (int kk = 0; kk < 2; ++kk) {
      const int kb = (kk * 64 + ((lane >> 4) << 4)) ^ swz;
      short8 af[4], bf[4];
#pragma unroll
      for (int m = 0; m < 4; ++m)
        af[m] = *(const short8*)(Ab + (wm * 64 + m * 16 + rsel) * 128 + kb);
#pragma unroll
      for (int n = 0; n < 4; ++n)
        bf[n] = *(const short8*)(Bb + (wn * 64 + n * 16 + rsel) * 128 + kb);
      __builtin_amdgcn_s_setprio(1);
#pragma unroll
      for (int m = 0; m < 4; ++m)
#pragma unroll
        for (int n = 0; n < 4; ++n)
          acc[m][n] = __builtin_amdgcn_mfma_f32_16x16x32_bf16(
              af[m], bf[n], acc[m][n], 0, 0, 0);
      __builtin_amdgcn_s_setprio(0);
    }
  };

  const int nk = K >> 6;             // 12
  STAGE(0, 0);
  STAGE(1, 1);
  for (int kt = 0; kt < nk; ++kt) {
    // gate: tile kt's 6 loads landed; tile kt+1's 6 may stay in flight
    if (kt < nk - 1)
      asm volatile("s_waitcnt vmcnt(6)" ::: "memory");
    else
      asm volatile("s_waitcnt vmcnt(0)" ::: "memory");
    __builtin_amdgcn_s_barrier();     // publish loads; certify kt-1 reads done
    asm volatile("" ::: "memory");    // no LDS-read hoisting above barrier
    if (kt + 2 < nk) STAGE((kt + 2) % 3, kt + 2);
    COMPUTE(kt % 3);
  }

  // C/D layout: col = lane&15, row = (lane>>4)*4 + j
  const int fr = lane & 15, fq = lane >> 4;
  if (ENC) {
    // B'' rows [n0+wn*64, +64) = {re,im} of cols cbase..cbase+31
    const int cbase = (n0 + wn * 64) >> 1;
    unsigned short* o = (unsigned short*)out;
#pragma unroll
    for (int n = 0; n < 2; ++n) {
      const int gcol = cbase + n * 16 + fr;
      const float br = bias_re[gcol], bi = bias_im[gcol];
#pragma unroll
      for (int m = 0; m < 4; ++m) {
        const int grow = m0 + wm * 64 + m * 16 + fq * 4;
#pragma unroll
        for (int j = 0; j < 4; ++j) {
          const float re = acc[m][n][j] + br;
          const float im = acc[m][n + 2][j] + bi;
          o[(size_t)(grow + j) * 768 + gcol] =
              f32_to_bf16(sqrtf(re * re + im * im));
        }
      }
    }
  } else {
    float* o = (float*)out;
#pragma unroll
    for (int n = 0; n < 4; ++n) {
      const int gcol = n0 + wn * 64 + n * 16 + fr;
      const float bv = bias_re[gcol];
#pragma unroll
      for (int m = 0; m < 4; ++m) {
        const int grow = m0 + wm * 64 + m * 16 + fq * 4;
#pragma unroll
        for (int j = 0; j < 4; ++j)
          o[(size_t)(grow + j) * 768 + gcol] = acc[m][n][j] + bv;
      }
    }
  }
}

// ---------------- launcher ---------------------------------------------------
extern "C" void kernel_launch(void* const* d_in, const int* in_sizes, int n_in,
                              void* d_out, int out_size, void* d_ws,
                              size_t ws_size, hipStream_t stream) {
  const float* x   = (const float*)d_in[0];
  const float* We  = (const float*)d_in[1];
  const float* be  = (const float*)d_in[2];
  const float* fre = (const float*)d_in[3];
  const float* fim = (const float*)d_in[4];
  const float* Wd  = (const float*)d_in[5];
  const float* bd  = (const float*)d_in[6];

  const int E = 768, C = 768;
  const int nX = in_sizes[0];                  // 19,267,584
  const int M  = nX / E;                       // 25088
  const int nW = E * C;                        // 589,824

  char* w = (char*)d_ws;
  unsigned short* xb    = (unsigned short*)w;                    // nX bf16
  unsigned short* Wdb   = (unsigned short*)(w + (size_t)nX * 2); // nW bf16
  unsigned short* Bpp   = Wdb + nW;                              // 2*nW bf16
  float*          be_re = (float*)(Bpp + 2 * (size_t)nW);
  float*          be_im = be_re + C;
  unsigned short* hb    = (unsigned short*)(be_im + C);          // nX bf16

  cvt_f32_bf16<<<(nX / 8 + 255) / 256, 256, 0, stream>>>(x, xb, nX / 8);
  cvt_f32_bf16<<<(nW / 8 + 255) / 256, 256, 0, stream>>>(Wd, Wdb, nW / 8);

  // fold ifft2(fft2(.)*filt)/256 into interleaved complex encoder weights
  fold_filter<<<145, 256, 0, stream>>>(We, be, fre, fim, Bpp, be_re, be_im);

  // a = |x @ We'^T + be'|  (bf16, in ws); grid 98*12 = 1176
  const int nbx1 = (2 * C) / 128;              // 12
  gemm_d3<1><<<nbx1 * (M / 256), 512, 0, stream>>>(xb, Bpp, be_re, be_im, hb,
                                                   M, E, nbx1);

  // out = a @ Wd^T + bd  (f32); grid 98*6 = 588
  const int nbx2 = E / 128;                    // 6
  gemm_d3<0><<<nbx2 * (M / 256), 512, 0, stream>>>(hb, Wdb, bd, nullptr,
                                                   (float*)d_out, M, C, nbx2);
}